// Round 1
// baseline (1991.109 us; speedup 1.0000x reference)
//
#include <hip/hip_runtime.h>
#include <hip/hip_bf16.h>
#include <math.h>

#define KIMG 8
#define HH 128
#define WW 128
#define NTOK (HH*WW)
#define DD 768
#define CC 10
#define NITER 5

// ---------- wave helpers ----------
__device__ __forceinline__ float rl63(float x){
  return __int_as_float(__builtin_amdgcn_readlane(__float_as_int(x), 63));
}
template<int CTRL,int RMASK>
__device__ __forceinline__ float dppadd(float x){
  int y = __builtin_amdgcn_update_dpp(0, __float_as_int(x), CTRL, RMASK, 0xf, true);
  return x + __int_as_float(y);
}
// full-wave sum; total lands in lane 63 (row_shr 1,2,4,8 then bcast15, bcast31)
__device__ __forceinline__ float wredsum(float x){
  x = dppadd<0x111,0xf>(x);
  x = dppadd<0x112,0xf>(x);
  x = dppadd<0x114,0xf>(x);
  x = dppadd<0x118,0xf>(x);
  x = dppadd<0x142,0xa>(x);
  x = dppadd<0x143,0xc>(x);
  return x;
}
// raw_h / raw_w arrive as 1-element arrays; dtype could be int32 or float32.
__device__ __forceinline__ float read_dim_f(const int* p){
  int v = *p;
  if (v > 0 && v < (1<<20)) return (float)v;   // plausible integer
  return __int_as_float(v);                    // else it was float bits
}

// ---------- 1. compact valid token indices (deterministic order) ----------
__global__ __launch_bounds__(256) void compact_kernel(const float* __restrict__ mask,
    int* __restrict__ vidx, int* __restrict__ vcnt){
  int k = blockIdx.x, tid = threadIdx.x;
  __shared__ int s[256];
  const float* mk = mask + (size_t)k*NTOK;
  int base = tid*64, c = 0;
  for (int j=0;j<64;j++) c += (mk[base+j] > 0.f) ? 1 : 0;
  s[tid] = c; __syncthreads();
  for (int st=1; st<256; st<<=1){
    int v = s[tid]; int u = (tid>=st) ? s[tid-st] : 0;
    __syncthreads(); s[tid] = v+u; __syncthreads();
  }
  int off = s[tid] - c;          // exclusive prefix
  if (tid==255) vcnt[k] = s[255];
  int* vk = vidx + (size_t)k*NTOK;
  for (int j=0;j<64;j++){ if (mk[base+j] > 0.f) vk[off++] = base+j; }
}

// ---------- 2. initial centroids = tokens[init_idx] ----------
__global__ __launch_bounds__(256) void init_kernel(const float* __restrict__ feat,
  const float* __restrict__ boxes, const float* __restrict__ Wp, const float* __restrict__ bp,
  const int* __restrict__ iidx, const int* __restrict__ prawh, const int* __restrict__ praww,
  float* __restrict__ cent){
  int k = blockIdx.x, tid = threadIdx.x;
  float top = boxes[k*4+0], lft = boxes[k*4+1], bot = boxes[k*4+2], rgt = boxes[k*4+3];
  float rh = read_dim_f(prawh), rw = read_dim_f(praww);
  float inv_rw = 1.f/(rw-1.f), inv_rh = 1.f/(rh-1.f);
  float xs = (rgt-lft)*(1.f/(float)WW), ys = (bot-top)*(1.f/(float)HH);
  for (int c=0;c<CC;c++){
    int tok = iidx[k*CC+c];
    int h = tok>>7, w = tok&127;
    float xg = fminf(fmaxf(((float)w*xs+lft)*inv_rw,0.f),1.f);
    float yg = fminf(fmaxf(((float)h*ys+top)*inv_rh,0.f),1.f);
    const float* fp = feat + ((size_t)k*NTOK + tok)*DD;
    float* cp = cent + ((size_t)k*CC + c)*DD;
    for (int d=tid; d<DD; d+=256)
      cp[d] = fp[d] + xg*Wp[d] + yg*Wp[DD+d] + bp[d];
  }
}

// ---------- 3. assignment + per-block partial sums (the hot kernel) ----------
__global__ __launch_bounds__(256) void assign_kernel(
    const float* __restrict__ feat, const float* __restrict__ boxes,
    const float* __restrict__ Wp, const float* __restrict__ bp,
    const int* __restrict__ prawh, const int* __restrict__ praww,
    const float* __restrict__ cent, const int* __restrict__ vidx, const int* __restrict__ vcnt,
    float* __restrict__ fsums, float* __restrict__ osxg, float* __restrict__ osyg,
    int* __restrict__ ocnt, int G)
{
  int g = blockIdx.x, k = blockIdx.y;
  int tid = threadIdx.x, lane = tid & 63, wv = tid >> 6;
  __shared__ float s_sums[CC*DD];
  __shared__ float s_sxg[CC], s_syg[CC];
  __shared__ int   s_cnt[CC];
  for (int i=tid;i<CC*DD;i+=256) s_sums[i]=0.f;
  if (tid<CC){ s_sxg[tid]=0.f; s_syg[tid]=0.f; s_cnt[tid]=0; }
  __syncthreads();

  // centroids resident in registers: lane owns dims {lane, lane+64, ..., lane+704}
  float creg[CC][12];
  const float* ck = cent + (size_t)k*CC*DD;
  #pragma unroll
  for (int c=0;c<CC;c++)
    #pragma unroll
    for (int j=0;j<12;j++)
      creg[c][j] = ck[c*DD + j*64 + lane];

  // per-cluster scalars: A = ||c||^2 - 2 bp.c ; W0c = Wp0.c ; W1c = Wp1.c
  float sA[CC], sW0[CC], sW1[CC];
  {
    float w0[12], w1[12], bpv[12];
    #pragma unroll
    for (int j=0;j<12;j++){ w0[j]=Wp[j*64+lane]; w1[j]=Wp[DD+j*64+lane]; bpv[j]=bp[j*64+lane]; }
    #pragma unroll
    for (int c=0;c<CC;c++){
      float a0=0,a1=0,ab=0,an=0;
      #pragma unroll
      for (int j=0;j<12;j++){
        float cv=creg[c][j];
        a0=fmaf(cv,w0[j],a0); a1=fmaf(cv,w1[j],a1);
        ab=fmaf(cv,bpv[j],ab); an=fmaf(cv,cv,an);
      }
      a0=wredsum(a0); a1=wredsum(a1); ab=wredsum(ab); an=wredsum(an);
      float Av = an - 2.f*ab;
      sA[c]=rl63(Av); sW0[c]=rl63(a0); sW1[c]=rl63(a1);
    }
  }

  float top = boxes[k*4+0], lft = boxes[k*4+1], bot = boxes[k*4+2], rgt = boxes[k*4+3];
  float rh = read_dim_f(prawh), rw = read_dim_f(praww);
  float inv_rw = 1.f/(rw-1.f), inv_rh = 1.f/(rh-1.f);
  float xs = (rgt-lft)*(1.f/(float)WW), ys = (bot-top)*(1.f/(float)HH);

  int count = vcnt[k];
  int chunk = (count + G - 1)/G;
  int base  = g*chunk;
  int end   = min(base+chunk, count);

  const int* vk = vidx + (size_t)k*NTOK;
  auto load_tok = [&](int i, float* t, int& tok){
    tok = vk[i];
    const float* fp = feat + ((size_t)k*NTOK + (size_t)tok)*DD + lane;
    #pragma unroll
    for (int j=0;j<12;j++) t[j] = fp[j*64];
  };

  int i = base + wv;                 // waves interleave tokens
  float tc[12]; int tokc = 0;
  if (i < end) load_tok(i, tc, tokc);
  while (i < end){
    int inext = i + 4;
    float tn[12]; int tokn = 0;
    if (inext < end) load_tok(inext, tn, tokn);   // prefetch next token

    int h = tokc>>7, w = tokc&127;
    float xg = fminf(fmaxf(((float)w*xs+lft)*inv_rw,0.f),1.f);
    float yg = fminf(fmaxf(((float)h*ys+top)*inv_rh,0.f),1.f);

    float acc[CC];
    #pragma unroll
    for (int c=0;c<CC;c++) acc[c]=0.f;
    #pragma unroll
    for (int j=0;j<12;j++)
      #pragma unroll
      for (int c=0;c<CC;c++) acc[c]=fmaf(tc[j],creg[c][j],acc[c]);
    #pragma unroll
    for (int c=0;c<CC;c++) acc[c]=wredsum(acc[c]);

    float m2xg=-2.f*xg, m2yg=-2.f*yg;
    float best=0.f; int bl=0;
    #pragma unroll
    for (int c=0;c<CC;c++){
      float dot = rl63(acc[c]);
      float sc = fmaf(m2xg,sW0[c], fmaf(m2yg,sW1[c], fmaf(-2.f,dot,sA[c])));
      if (c==0){ best=sc; } else if (sc<best){ best=sc; bl=c; }
    }

    float* sb = s_sums + bl*DD;      // stride-64 addressing: conflict-free ds_add
    #pragma unroll
    for (int j=0;j<12;j++) atomicAdd(&sb[j*64+lane], tc[j]);
    if (lane==0){
      atomicAdd(&s_cnt[bl],1);
      atomicAdd(&s_sxg[bl],xg);
      atomicAdd(&s_syg[bl],yg);
    }

    i = inext;
    if (i < end){
      #pragma unroll
      for (int j=0;j<12;j++) tc[j]=tn[j];
      tokc = tokn;
    }
  }
  __syncthreads();

  float* fo = fsums + ((size_t)(k*G+g))*CC*DD;
  for (int x=tid;x<CC*DD;x+=256) fo[x]=s_sums[x];
  if (tid<CC){
    size_t o = (size_t)(k*G+g)*CC + tid;
    osxg[o]=s_sxg[tid]; osyg[o]=s_syg[tid]; ocnt[o]=s_cnt[tid];
  }
}

// ---------- 4. deterministic reduce over G partials + centroid update ----------
__global__ __launch_bounds__(256) void update_kernel(
  const float* __restrict__ fsums, const float* __restrict__ osxg, const float* __restrict__ osyg,
  const int* __restrict__ ocnt, const float* __restrict__ Wp, const float* __restrict__ bp,
  float* __restrict__ cent, int G)
{
  int idx = blockIdx.x*256 + threadIdx.x;   // over K*C*D ; 768 = 3*256 so kc uniform/block
  int d  = idx % DD;
  int kc = idx / DD;
  int k  = kc / CC, c = kc % CC;
  __shared__ float sX[64], sY[64]; __shared__ int sN[64];
  if (threadIdx.x < 64){
    int g = threadIdx.x;
    if (g < G){
      size_t o = (size_t)(k*G+g)*CC + c;
      sX[g]=osxg[o]; sY[g]=osyg[o]; sN[g]=ocnt[o];
    } else { sX[g]=0.f; sY[g]=0.f; sN[g]=0; }
  }
  __syncthreads();
  int n=0; float sx=0.f, sy=0.f;
  for (int t=0;t<64;t++){ n+=sN[t]; sx+=sX[t]; sy+=sY[t]; }
  float s=0.f;
  for (int g=0; g<G; g++)
    s += fsums[((size_t)(k*G+g)*CC + c)*DD + d];
  if (n > 0){
    float nf = (float)n;
    float ts = s + sx*Wp[d] + sy*Wp[DD+d] + nf*bp[d];  // re-apply factored posenc
    cent[(size_t)kc*DD + d] = ts / nf;
  } // else keep old centroid (leave memory untouched)
}

// ---------- 5. Linear-GELU-Linear on the 80 centroid rows ----------
__global__ __launch_bounds__(768) void mlp_kernel(const float* __restrict__ cent,
  const float* __restrict__ W1, const float* __restrict__ b1,
  const float* __restrict__ W2, const float* __restrict__ b2,
  float* __restrict__ out)
{
  int k = blockIdx.x, col = threadIdx.x;
  __shared__ float srow[CC][DD];
  __shared__ float sh1[CC][DD];
  #pragma unroll
  for (int r=0;r<CC;r++) srow[r][col] = cent[((size_t)k*CC+r)*DD + col];
  __syncthreads();
  float acc[CC];
  #pragma unroll
  for (int r=0;r<CC;r++) acc[r]=0.f;
  for (int dd=0; dd<DD; dd++){
    float wv = W1[(size_t)dd*DD + col];
    #pragma unroll
    for (int r=0;r<CC;r++) acc[r] = fmaf(srow[r][dd], wv, acc[r]);
  }
  float bb = b1[col];
  #pragma unroll
  for (int r=0;r<CC;r++){
    float x = acc[r] + bb;
    sh1[r][col] = 0.5f*x*(1.f+erff(x*0.70710678118654752440f));  // exact gelu
  }
  __syncthreads();
  #pragma unroll
  for (int r=0;r<CC;r++) acc[r]=0.f;
  for (int dd=0; dd<DD; dd++){
    float wv = W2[(size_t)dd*DD + col];
    #pragma unroll
    for (int r=0;r<CC;r++) acc[r] = fmaf(sh1[r][dd], wv, acc[r]);
  }
  float bb2 = b2[col];
  #pragma unroll
  for (int r=0;r<CC;r++) out[((size_t)k*CC+r)*DD + col] = acc[r] + bb2;
}

// ---------- launch ----------
extern "C" void kernel_launch(void* const* d_in, const int* in_sizes, int n_in,
                              void* d_out, int out_size, void* d_ws, size_t ws_size,
                              hipStream_t stream)
{
  const float* feat = (const float*)d_in[0];
  const float* mask = (const float*)d_in[1];
  const float* boxes= (const float*)d_in[2];
  const float* Wp   = (const float*)d_in[3];
  const float* bp   = (const float*)d_in[4];
  const float* W1   = (const float*)d_in[5];
  const float* b1   = (const float*)d_in[6];
  const float* W2   = (const float*)d_in[7];
  const float* b2   = (const float*)d_in[8];
  const int*   iidx = (const int*)d_in[9];
  const int*   prawh= (const int*)d_in[10];
  const int*   praww= (const int*)d_in[11];
  float* out = (float*)d_out;

  auto align = [](size_t x){ return (x + 255) & ~(size_t)255; };
  int G = 64;
  size_t o_cent=0,o_vidx=0,o_vcnt=0,o_fs=0,o_sx=0,o_sy=0,o_cn=0,total=0;
  for (;;){
    size_t off = 0;
    o_cent = off; off = align(off + (size_t)KIMG*CC*DD*4);
    o_vidx = off; off = align(off + (size_t)KIMG*NTOK*4);
    o_vcnt = off; off = align(off + (size_t)KIMG*4);
    o_fs   = off; off = align(off + (size_t)KIMG*G*CC*DD*4);
    o_sx   = off; off = align(off + (size_t)KIMG*G*CC*4);
    o_sy   = off; off = align(off + (size_t)KIMG*G*CC*4);
    o_cn   = off; off = align(off + (size_t)KIMG*G*CC*4);
    total = off;
    if (total <= ws_size || G == 1) break;
    G >>= 1;
  }
  char* ws = (char*)d_ws;
  float* cent  = (float*)(ws + o_cent);
  int*   vidx  = (int*)  (ws + o_vidx);
  int*   vcnt  = (int*)  (ws + o_vcnt);
  float* fsums = (float*)(ws + o_fs);
  float* sxg   = (float*)(ws + o_sx);
  float* syg   = (float*)(ws + o_sy);
  int*   ocnt  = (int*)  (ws + o_cn);

  compact_kernel<<<KIMG,256,0,stream>>>(mask, vidx, vcnt);
  init_kernel<<<KIMG,256,0,stream>>>(feat, boxes, Wp, bp, iidx, prawh, praww, cent);
  for (int it=0; it<NITER; ++it){
    assign_kernel<<<dim3(G,KIMG),256,0,stream>>>(feat, boxes, Wp, bp, prawh, praww,
        cent, vidx, vcnt, fsums, sxg, syg, ocnt, G);
    update_kernel<<<(KIMG*CC*DD)/256,256,0,stream>>>(fsums, sxg, syg, ocnt, Wp, bp, cent, G);
  }
  mlp_kernel<<<KIMG,768,0,stream>>>(cent, W1, b1, W2, b2, out);
}

// Round 2
// 1957.217 us; speedup vs baseline: 1.0173x; 1.0173x over previous
//
#include <hip/hip_runtime.h>
#include <hip/hip_bf16.h>
#include <math.h>

#define KIMG 8
#define HH 128
#define WW 128
#define NTOK (HH*WW)
#define DD 768
#define CC 10
#define NITER 5

// ---------- wave helpers ----------
__device__ __forceinline__ float rl63(float x){
  return __int_as_float(__builtin_amdgcn_readlane(__float_as_int(x), 63));
}
template<int CTRL,int RMASK>
__device__ __forceinline__ float dppadd(float x){
  int y = __builtin_amdgcn_update_dpp(0, __float_as_int(x), CTRL, RMASK, 0xf, true);
  return x + __int_as_float(y);
}
// full-wave sum; total lands in lane 63
__device__ __forceinline__ float wredsum(float x){
  x = dppadd<0x111,0xf>(x);
  x = dppadd<0x112,0xf>(x);
  x = dppadd<0x114,0xf>(x);
  x = dppadd<0x118,0xf>(x);
  x = dppadd<0x142,0xa>(x);
  x = dppadd<0x143,0xc>(x);
  return x;
}
__device__ __forceinline__ float read_dim_f(const int* p){
  int v = *p;
  if (v > 0 && v < (1<<20)) return (float)v;   // plausible integer
  return __int_as_float(v);                    // else float bits
}

union F4 { float4 v; float f[4]; };

// ---------- 1. compact valid token indices (deterministic order) ----------
__global__ __launch_bounds__(256) void compact_kernel(const float* __restrict__ mask,
    int* __restrict__ vidx, int* __restrict__ vcnt){
  int k = blockIdx.x, tid = threadIdx.x;
  __shared__ int s[256];
  const float* mk = mask + (size_t)k*NTOK;
  int base = tid*64, c = 0;
  for (int j=0;j<64;j++) c += (mk[base+j] > 0.f) ? 1 : 0;
  s[tid] = c; __syncthreads();
  for (int st=1; st<256; st<<=1){
    int v = s[tid]; int u = (tid>=st) ? s[tid-st] : 0;
    __syncthreads(); s[tid] = v+u; __syncthreads();
  }
  int off = s[tid] - c;          // exclusive prefix
  if (tid==255) vcnt[k] = s[255];
  int* vk = vidx + (size_t)k*NTOK;
  for (int j=0;j<64;j++){ if (mk[base+j] > 0.f) vk[off++] = base+j; }
}

// ---------- 2. initial centroids = tokens[init_idx] (logical d layout) ----------
__global__ __launch_bounds__(256) void init_kernel(const float* __restrict__ feat,
  const float* __restrict__ boxes, const float* __restrict__ Wp, const float* __restrict__ bp,
  const int* __restrict__ iidx, const int* __restrict__ prawh, const int* __restrict__ praww,
  float* __restrict__ cent){
  int k = blockIdx.x, tid = threadIdx.x;
  float top = boxes[k*4+0], lft = boxes[k*4+1], bot = boxes[k*4+2], rgt = boxes[k*4+3];
  float rh = read_dim_f(prawh), rw = read_dim_f(praww);
  float inv_rw = 1.f/(rw-1.f), inv_rh = 1.f/(rh-1.f);
  float xs = (rgt-lft)*(1.f/(float)WW), ys = (bot-top)*(1.f/(float)HH);
  for (int c=0;c<CC;c++){
    int tok = iidx[k*CC+c];
    int h = tok>>7, w = tok&127;
    float xg = fminf(fmaxf(((float)w*xs+lft)*inv_rw,0.f),1.f);
    float yg = fminf(fmaxf(((float)h*ys+top)*inv_rh,0.f),1.f);
    const float* fp = feat + ((size_t)k*NTOK + tok)*DD;
    float* cp = cent + ((size_t)k*CC + c)*DD;
    for (int d=tid; d<DD; d+=256)
      cp[d] = fp[d] + xg*Wp[d] + yg*Wp[DD+d] + bp[d];
  }
}

// ---------- 3. assignment + per-block partial sums (hot) ----------
// lane owns dims d = 256*j + 4*lane + m  (j=0..2, m=0..3) -> 3x dwordx4 per token
// LDS partial sums stored PHYSICALLY at p = j*256 + m*64 + lane (conflict-free ds_add)
__global__ __launch_bounds__(256,2) void assign_kernel(
    const float* __restrict__ feat, const float* __restrict__ boxes,
    const float* __restrict__ Wp, const float* __restrict__ bp,
    const int* __restrict__ prawh, const int* __restrict__ praww,
    const float* __restrict__ cent, const int* __restrict__ vidx, const int* __restrict__ vcnt,
    float* __restrict__ fsums, float* __restrict__ osxg, float* __restrict__ osyg,
    int* __restrict__ ocnt, int G)
{
  int g = blockIdx.x, k = blockIdx.y;
  int tid = threadIdx.x, lane = tid & 63, wv = tid >> 6;
  __shared__ float s_sums[CC*DD];
  __shared__ float s_sxg[CC], s_syg[CC];
  __shared__ int   s_cnt[CC];
  for (int i=tid;i<CC*DD;i+=256) s_sums[i]=0.f;
  if (tid<CC){ s_sxg[tid]=0.f; s_syg[tid]=0.f; s_cnt[tid]=0; }
  __syncthreads();

  // centroids in registers (will be scaled by -2 after scalar precompute)
  F4 creg[CC][3];
  {
    const float* ck = cent + (size_t)k*CC*DD + 4*lane;
    #pragma unroll
    for (int c=0;c<CC;c++)
      #pragma unroll
      for (int j=0;j<3;j++)
        creg[c][j].v = *(const float4*)(ck + c*DD + j*256);
  }

  // per-cluster scalars: sA = ||c||^2 - 2 bp.c ; sW0 = -2 Wp0.c ; sW1 = -2 Wp1.c
  float sA[CC], sW0[CC], sW1[CC];
  {
    F4 w0[3], w1[3], bb[3];
    #pragma unroll
    for (int j=0;j<3;j++){
      w0[j].v = *(const float4*)(Wp + j*256 + 4*lane);
      w1[j].v = *(const float4*)(Wp + DD + j*256 + 4*lane);
      bb[j].v = *(const float4*)(bp + j*256 + 4*lane);
    }
    #pragma unroll
    for (int c=0;c<CC;c++){
      float a0=0.f,a1=0.f,ab=0.f,an=0.f;
      #pragma unroll
      for (int j=0;j<3;j++)
        #pragma unroll
        for (int m=0;m<4;m++){
          float cv = creg[c][j].f[m];
          a0=fmaf(cv,w0[j].f[m],a0); a1=fmaf(cv,w1[j].f[m],a1);
          ab=fmaf(cv,bb[j].f[m],ab); an=fmaf(cv,cv,an);
        }
      a0=wredsum(-2.f*a0); a1=wredsum(-2.f*a1);
      ab=wredsum(ab); an=wredsum(an);
      sA[c]  = rl63(fmaf(-2.f,ab,an));
      sW0[c] = rl63(a0);
      sW1[c] = rl63(a1);
    }
    // scale centroids by -2 so the per-token score is sA + dot' + xg*sW0 + yg*sW1
    #pragma unroll
    for (int c=0;c<CC;c++)
      #pragma unroll
      for (int j=0;j<3;j++)
        #pragma unroll
        for (int m=0;m<4;m++)
          creg[c][j].f[m] *= -2.f;
  }

  float top = boxes[k*4+0], lft = boxes[k*4+1], bot = boxes[k*4+2], rgt = boxes[k*4+3];
  float rh = read_dim_f(prawh), rw = read_dim_f(praww);
  float inv_rw = 1.f/(rw-1.f), inv_rh = 1.f/(rh-1.f);
  float xs = (rgt-lft)*(1.f/(float)WW), ys = (bot-top)*(1.f/(float)HH);

  int count = vcnt[k];
  int chunk = (count + G - 1)/G;
  int base  = g*chunk;
  int end   = min(base+chunk, count);
  const int* vk = vidx + (size_t)k*NTOK;

  if (base < end){
    int iters = (end - base + 3) >> 2;
    int i = base + wv;

    F4 cur[3], n1[3], n2[3];
    int tokc, tok1, tok2;

    auto LOAD = [&](int idx, F4* t, int& tok){
      int ic = (idx < end) ? idx : (end-1);
      tok = __builtin_amdgcn_readfirstlane(vk[ic]);
      const float* fp = feat + ((size_t)k*NTOK + (size_t)tok)*DD + 4*lane;
      t[0].v = *(const float4*)(fp);
      t[1].v = *(const float4*)(fp+256);
      t[2].v = *(const float4*)(fp+512);
    };
    LOAD(i,   cur, tokc);
    LOAD(i+4, n1,  tok1);

    for (int it=0; it<iters; ++it){
      LOAD(i+8, n2, tok2);                 // depth-2 prefetch (clamped, uniform)
      bool vld = (i < end);

      int h = tokc>>7, w = tokc&127;
      float xg = fminf(fmaxf(((float)w*xs+lft)*inv_rw,0.f),1.f);
      float yg = fminf(fmaxf(((float)h*ys+top)*inv_rh,0.f),1.f);

      float acc[CC];
      #pragma unroll
      for (int c=0;c<CC;c++) acc[c]=0.f;
      #pragma unroll
      for (int j=0;j<3;j++)
        #pragma unroll
        for (int m=0;m<4;m++){
          float tv = cur[j].f[m];
          #pragma unroll
          for (int c=0;c<CC;c++) acc[c]=fmaf(tv,creg[c][j].f[m],acc[c]);
        }
      #pragma unroll
      for (int c=0;c<CC;c++) acc[c]=wredsum(acc[c]);

      float best=3.4e38f; int bl=0;
      #pragma unroll
      for (int c=0;c<CC;c++){
        float sc = rl63(acc[c]) + sA[c] + xg*sW0[c] + yg*sW1[c];
        if (sc < best){ best=sc; bl=c; }
      }

      if (vld){
        float* sb = s_sums + bl*DD + lane;   // physical layout: j*256 + m*64 + lane
        #pragma unroll
        for (int j=0;j<3;j++)
          #pragma unroll
          for (int m=0;m<4;m++)
            atomicAdd(&sb[j*256 + m*64], cur[j].f[m]);
        if (lane==0){
          atomicAdd(&s_cnt[bl],1);
          atomicAdd(&s_sxg[bl],xg);
          atomicAdd(&s_syg[bl],yg);
        }
      }

      #pragma unroll
      for (int j=0;j<3;j++){ cur[j]=n1[j]; n1[j]=n2[j]; }
      tokc=tok1; tok1=tok2;
      i += 4;
    }
  }
  __syncthreads();

  float* fo = fsums + ((size_t)(k*G+g))*CC*DD;
  for (int x=tid;x<CC*DD;x+=256) fo[x]=s_sums[x];
  if (tid<CC){
    size_t o = (size_t)(k*G+g)*CC + tid;
    osxg[o]=s_sxg[tid]; osyg[o]=s_syg[tid]; ocnt[o]=s_cnt[tid];
  }
}

// ---------- 4. deterministic reduce over G partials + centroid update ----------
// fsums is in PHYSICAL layout p = j*256 + m*64 + l ; logical d = 256*j + 4*l + m
__global__ __launch_bounds__(256) void update_kernel(
  const float* __restrict__ fsums, const float* __restrict__ osxg, const float* __restrict__ osyg,
  const int* __restrict__ ocnt, const float* __restrict__ Wp, const float* __restrict__ bp,
  float* __restrict__ cent, int G)
{
  int idx = blockIdx.x*256 + threadIdx.x;   // over K*C*D ; DD%256==0 so kc uniform/block
  int d  = idx % DD;
  int kc = idx / DD;
  int k  = kc / CC, c = kc % CC;
  int j = d >> 8, r = d & 255, l = r >> 2, m = r & 3;
  int p = (j << 8) | (m << 6) | l;
  __shared__ float sX[64], sY[64]; __shared__ int sN[64];
  if (threadIdx.x < 64){
    int g = threadIdx.x;
    if (g < G){
      size_t o = (size_t)(k*G+g)*CC + c;
      sX[g]=osxg[o]; sY[g]=osyg[o]; sN[g]=ocnt[o];
    } else { sX[g]=0.f; sY[g]=0.f; sN[g]=0; }
  }
  __syncthreads();
  int n=0; float sx=0.f, sy=0.f;
  for (int t=0;t<64;t++){ n+=sN[t]; sx+=sX[t]; sy+=sY[t]; }
  float s=0.f;
  for (int g=0; g<G; g++)
    s += fsums[((size_t)(k*G+g)*CC + c)*DD + p];
  if (n > 0){
    float nf = (float)n;
    float ts = s + sx*Wp[d] + sy*Wp[DD+d] + nf*bp[d];  // factored posenc re-applied
    cent[(size_t)kc*DD + d] = ts / nf;
  } // else keep old centroid
}

// ---------- 5. MLP split into two kernels, 24 blocks each ----------
__global__ __launch_bounds__(256) void mlp1_kernel(const float* __restrict__ cent,
  const float* __restrict__ W1, const float* __restrict__ b1, float* __restrict__ h1)
{
  int k = blockIdx.y; int col = blockIdx.x*256 + threadIdx.x;
  __shared__ float srow[CC*DD];
  for (int x=threadIdx.x; x<CC*DD; x+=256) srow[x] = cent[(size_t)k*CC*DD + x];
  __syncthreads();
  float acc[CC];
  #pragma unroll
  for (int r=0;r<CC;r++) acc[r]=0.f;
  for (int dd=0; dd<DD; dd++){
    float wv = W1[(size_t)dd*DD + col];
    #pragma unroll
    for (int r=0;r<CC;r++) acc[r] = fmaf(srow[r*DD+dd], wv, acc[r]);
  }
  float bb = b1[col];
  #pragma unroll
  for (int r=0;r<CC;r++){
    float x = acc[r] + bb;
    h1[((size_t)k*CC+r)*DD + col] = 0.5f*x*(1.f+erff(x*0.70710678118654752440f));
  }
}

__global__ __launch_bounds__(256) void mlp2_kernel(const float* __restrict__ h1,
  const float* __restrict__ W2, const float* __restrict__ b2, float* __restrict__ out)
{
  int k = blockIdx.y; int col = blockIdx.x*256 + threadIdx.x;
  __shared__ float srow[CC*DD];
  for (int x=threadIdx.x; x<CC*DD; x+=256) srow[x] = h1[(size_t)k*CC*DD + x];
  __syncthreads();
  float acc[CC];
  #pragma unroll
  for (int r=0;r<CC;r++) acc[r]=0.f;
  for (int dd=0; dd<DD; dd++){
    float wv = W2[(size_t)dd*DD + col];
    #pragma unroll
    for (int r=0;r<CC;r++) acc[r] = fmaf(srow[r*DD+dd], wv, acc[r]);
  }
  float bb = b2[col];
  #pragma unroll
  for (int r=0;r<CC;r++) out[((size_t)k*CC+r)*DD + col] = acc[r] + bb;
}

// ---------- launch ----------
extern "C" void kernel_launch(void* const* d_in, const int* in_sizes, int n_in,
                              void* d_out, int out_size, void* d_ws, size_t ws_size,
                              hipStream_t stream)
{
  const float* feat = (const float*)d_in[0];
  const float* mask = (const float*)d_in[1];
  const float* boxes= (const float*)d_in[2];
  const float* Wp   = (const float*)d_in[3];
  const float* bp   = (const float*)d_in[4];
  const float* W1   = (const float*)d_in[5];
  const float* b1   = (const float*)d_in[6];
  const float* W2   = (const float*)d_in[7];
  const float* b2   = (const float*)d_in[8];
  const int*   iidx = (const int*)d_in[9];
  const int*   prawh= (const int*)d_in[10];
  const int*   praww= (const int*)d_in[11];
  float* out = (float*)d_out;

  auto align = [](size_t x){ return (x + 255) & ~(size_t)255; };
  int G = 64;
  size_t o_cent=0,o_vidx=0,o_vcnt=0,o_fs=0,o_sx=0,o_sy=0,o_cn=0,o_h1=0,total=0;
  for (;;){
    size_t off = 0;
    o_cent = off; off = align(off + (size_t)KIMG*CC*DD*4);
    o_vidx = off; off = align(off + (size_t)KIMG*NTOK*4);
    o_vcnt = off; off = align(off + (size_t)KIMG*4);
    o_h1   = off; off = align(off + (size_t)KIMG*CC*DD*4);
    o_fs   = off; off = align(off + (size_t)KIMG*G*CC*DD*4);
    o_sx   = off; off = align(off + (size_t)KIMG*G*CC*4);
    o_sy   = off; off = align(off + (size_t)KIMG*G*CC*4);
    o_cn   = off; off = align(off + (size_t)KIMG*G*CC*4);
    total = off;
    if (total <= ws_size || G == 1) break;
    G >>= 1;
  }
  char* ws = (char*)d_ws;
  float* cent  = (float*)(ws + o_cent);
  int*   vidx  = (int*)  (ws + o_vidx);
  int*   vcnt  = (int*)  (ws + o_vcnt);
  float* h1    = (float*)(ws + o_h1);
  float* fsums = (float*)(ws + o_fs);
  float* sxg   = (float*)(ws + o_sx);
  float* syg   = (float*)(ws + o_sy);
  int*   ocnt  = (int*)  (ws + o_cn);

  compact_kernel<<<KIMG,256,0,stream>>>(mask, vidx, vcnt);
  init_kernel<<<KIMG,256,0,stream>>>(feat, boxes, Wp, bp, iidx, prawh, praww, cent);
  for (int it=0; it<NITER; ++it){
    assign_kernel<<<dim3(G,KIMG),256,0,stream>>>(feat, boxes, Wp, bp, prawh, praww,
        cent, vidx, vcnt, fsums, sxg, syg, ocnt, G);
    update_kernel<<<(KIMG*CC*DD)/256,256,0,stream>>>(fsums, sxg, syg, ocnt, Wp, bp, cent, G);
  }
  mlp1_kernel<<<dim3(3,KIMG),256,0,stream>>>(cent, W1, b1, h1);
  mlp2_kernel<<<dim3(3,KIMG),256,0,stream>>>(h1, W2, b2, out);
}